// Round 7
// baseline (123.338 us; speedup 1.0000x reference)
//
#include <hip/hip_runtime.h>
#include <hip/hip_bf16.h>
#include <cstdint>
#include <cstddef>
#include <math.h>

// Problem constants (reference: B=4096, D=256, T=0.5)
#define BSZ   4096
#define NROW  8192          // 2*B
#define DIM   256
#define INV_T 2.0f
#define EPS_N 1e-8f

typedef __attribute__((ext_vector_type(8))) short bf16x8;   // 8 bf16 = 4 VGPRs
typedef __attribute__((ext_vector_type(4))) float f32x4;

__device__ __forceinline__ unsigned short f2bf(float x) {
    __hip_bfloat16 h = __float2bfloat16(x);
    return __builtin_bit_cast(unsigned short, h);
}

// async global->LDS 16B helper (wave-uniform LDS base + lane*16 layout)
__device__ __forceinline__ void load_lds16(const void* g, void* l) {
    __builtin_amdgcn_global_load_lds(
        (const __attribute__((address_space(1))) void*)g,
        (__attribute__((address_space(3))) void*)l,
        16, 0, 0);
}

#define VMWAIT(N) asm volatile("s_waitcnt vmcnt(" #N ")" ::: "memory")

// ---------------------------------------------------------------------------
// zn2 staged layout (R5-verified): [strip(64)][kc(4)][row(128)][unit16(8)],
// XOR-swizzle baked in at write time:
//   zn2[s][kc][row][u] holds row bytes kc*128 + (u^(row&7))*16 .. +16
// => every gram stage is a pure sequential 16 KB stream; LDS image equals the
// verified swizzled layout; fragment-read side identical to R0.
//
// Kernel 1: row-normalize concat(z1,z2) into zn2 (R5 version, verified).
__global__ __launch_bounds__(256)
void nt_normalize(const float* __restrict__ z1,
                  const float* __restrict__ z2,
                  char* __restrict__ zn2,
                  float* __restrict__ rowsum) {
    const int wave = threadIdx.x >> 6;
    const int lane = threadIdx.x & 63;
    const int row  = blockIdx.x * 4 + wave;
    const float* src = (row < BSZ) ? (z1 + (size_t)row * DIM)
                                   : (z2 + (size_t)(row - BSZ) * DIM);
    const float4 v = ((const float4*)src)[lane];
    float ss = v.x * v.x + v.y * v.y + v.z * v.z + v.w * v.w;
    #pragma unroll
    for (int off = 32; off; off >>= 1) ss += __shfl_xor(ss, off);
    const float rinv = 1.0f / fmaxf(sqrtf(ss), EPS_N);  // torch eps clamp
    ushort4 o;
    o.x = f2bf(v.x * rinv);
    o.y = f2bf(v.y * rinv);
    o.z = f2bf(v.z * rinv);
    o.w = f2bf(v.w * rinv);
    // lane i holds row bytes [8i, 8i+8): kc=i>>4, unit=(i>>1)&7, half=i&1
    const int s    = row >> 7;
    const int lrow = row & 127;
    const int kc   = lane >> 4;
    const int unit = (lane >> 1) & 7;
    const int half = lane & 1;
    const int u    = unit ^ (lrow & 7);          // baked swizzle
    *(ushort4*)(zn2 + (size_t)s * 65536 + kc * 16384 + lrow * 128 + u * 16 + half * 8) = o;
    if (lane == 0) rowsum[row] = 0.0f;
}

// ---------------------------------------------------------------------------
// Kernel 2: PERSISTENT tiled Zn·Znᵀ. Grid = 256 blocks (1/CU, LDS-forced),
// 512 threads = 8 waves (2x4 grid of 64x32 wave-tiles on a 128x128 tile).
// Block k owns tiles [ceil(2080k/256), ceil(2080(k+1)/256)) of the R0
// triangular order (8-9 consecutive tiles). A-strip (128 rows, full K) is
// staged ONCE per strip into 64 KB LDS; B kc-slices (16 KB) stream through a
// double-buffered counted-vmcnt pipeline that is 32-36 steps long and NEVER
// drains mid-block. Theory: all six prior structures had only 4 K-steps per
// block (pipeline fill/drain dominated, ~10 B/cyc/CU plateau); this makes
// the tile stream the pipeline axis, reaching steady state like m97/m201.
__global__ __launch_bounds__(512, 2)
void nt_gram(const char* __restrict__ zn2,
             float* __restrict__ rowsum,
             float* __restrict__ pos) {
    __shared__ char Ab[65536];       // A strip: [kc(4)][row(128)][128 B]
    __shared__ char Bb[2][16384];    // B kc-slice double buffer

    // Block -> XCD-contiguous chunk of the triangular tile list.
    const int blk   = blockIdx.x;
    const int chunk = (blk & 7) * 32 + (blk >> 3);   // 256 = 8*32, bijective
    const int lo    = (65 * chunk) >> 3;             // 2080/256 = 65/8
    const int hi    = (65 * (chunk + 1)) >> 3;
    const int W     = (hi - lo) << 2;                // works = tiles * 4 kc

    // Triangular decode of first tile: S(bi) = 64*bi - bi*(bi-1)/2.
    int bi0 = (int)((129.0 - sqrt(16641.0 - 8.0 * (double)lo)) * 0.5);
    while (64 * (bi0 + 1) - (bi0 + 1) * bi0 / 2 <= lo) ++bi0;
    while (64 * bi0 - bi0 * (bi0 - 1) / 2 > lo) --bi0;
    const int bj0 = bi0 + (lo - (64 * bi0 - bi0 * (bi0 - 1) / 2));

    const int t    = threadIdx.x;
    const int lane = t & 63;
    const int wave = t >> 6;
    const int wrow = (wave >> 2) * 64;   // 0,64
    const int wcol = (wave & 3) * 32;    // 0,32,64,96
    const int q    = lane >> 4;
    const int r16  = lane & 15;
    const int sw   = r16 & 7;            // read-side swizzle key
    const int t16  = t * 16;

    auto STAGE_A = [&](int bi) {         // 64 KB sequential, 8 loads/thread
        const char* src = zn2 + (size_t)bi * 65536;
        #pragma unroll
        for (int j = 0; j < 8; ++j)
            load_lds16(src + j * 8192 + t16, Ab + j * 8192 + t16);
    };
    auto STAGE_B = [&](int bj, int kc, int slot) {  // 16 KB, 2 loads/thread
        const char* src = zn2 + (size_t)bj * 65536 + kc * 16384;
        load_lds16(src + t16, Bb[slot] + t16);
        load_lds16(src + 8192 + t16, Bb[slot] + 8192 + t16);
    };

    f32x4 acc[4][2] = {};

    auto COMPUTE = [&](int kc, int slot) {
        const char* As = Ab + kc * 16384;
        const char* Bs = Bb[slot];
        #pragma unroll
        for (int kk = 0; kk < 64; kk += 32) {
            const int cpos = (((kk >> 3) + q) ^ sw) << 4;
            bf16x8 af[4], bfv[2];
            #pragma unroll
            for (int mi = 0; mi < 4; ++mi)
                af[mi] = *(const bf16x8*)(As + (wrow + mi * 16 + r16) * 128 + cpos);
            #pragma unroll
            for (int ni = 0; ni < 2; ++ni)
                bfv[ni] = *(const bf16x8*)(Bs + (wcol + ni * 16 + r16) * 128 + cpos);
            __builtin_amdgcn_s_setprio(1);
            #pragma unroll
            for (int mi = 0; mi < 4; ++mi)
                #pragma unroll
                for (int ni = 0; ni < 2; ++ni)
                    acc[mi][ni] = __builtin_amdgcn_mfma_f32_16x16x32_bf16(
                        af[mi], bfv[ni], acc[mi][ni], 0, 0, 0);
            __builtin_amdgcn_s_setprio(0);
        }
    };

    int bi_c = bi0, bj_c = bj0;          // compute-side tile cursor
    int bi_s = bi0, bj_s = bj0;          // stage-side tile cursor
    bool pend_A = false;                 // A restage owed (strip changed)

    auto EPILOGUE = [&]() {              // R0-verified math, ni range = 2
        const bool diag = (bi_c == bj_c);
        float colp[2] = {0.f, 0.f};
        #pragma unroll
        for (int mi = 0; mi < 4; ++mi) {
            #pragma unroll
            for (int r = 0; r < 4; ++r) {
                const int grow = bi_c * 128 + wrow + mi * 16 + q * 4 + r;
                float s = 0.f;
                #pragma unroll
                for (int ni = 0; ni < 2; ++ni) {
                    const int gcol = bj_c * 128 + wcol + ni * 16 + r16;
                    const float val = acc[mi][ni][r];
                    float e = __expf(val * INV_T);
                    e = (grow == gcol) ? 0.f : e;   // exact diagonal exclusion
                    s += e;
                    colp[ni] += e;
                    if (gcol == grow + BSZ) {       // positive pair (bj==bi+32)
                        pos[grow] = val;            // tile unique to this block
                        pos[gcol] = val;
                    }
                }
                s += __shfl_xor(s, 1);
                s += __shfl_xor(s, 2);
                s += __shfl_xor(s, 4);
                s += __shfl_xor(s, 8);
                if (r16 == 0) atomicAdd(&rowsum[grow], s);
            }
        }
        if (!diag) {   // diag tiles: col sums would double-count (symmetry)
            #pragma unroll
            for (int ni = 0; ni < 2; ++ni) {
                float cs = colp[ni];
                cs += __shfl_xor(cs, 16);
                cs += __shfl_xor(cs, 32);
                if (q == 0) atomicAdd(&rowsum[bj_c * 128 + wcol + ni * 16 + r16], cs);
            }
        }
        #pragma unroll
        for (int mi = 0; mi < 4; ++mi)
            #pragma unroll
            for (int ni = 0; ni < 2; ++ni)
                acc[mi][ni] = (f32x4){0.f, 0.f, 0.f, 0.f};
    };

    // Prologue: A + first two B slices. vmcnt(2) retires A+B0, leaves B1.
    STAGE_A(bi0);
    STAGE_B(bj0, 0, 0);
    STAGE_B(bj0, 1, 1);
    VMWAIT(2);
    __builtin_amdgcn_s_barrier();

    // Steady state invariant at loop top: B_w in LDS, B_{w+1} sole in-flight.
    for (int w = 0; w < W; ++w) {
        const int kc = w & 3;
        COMPUTE(kc, w & 1);
        __builtin_amdgcn_s_barrier();          // all waves done with slot w&1
        if (pend_A) { STAGE_A(bi_s); pend_A = false; }   // before B: ledger ok
        const int  w2   = w + 2;
        const bool more = (w2 < W);
        if (more) {
            if ((w2 & 3) == 0) {               // stage cursor enters new tile
                if (++bj_s > 63) { ++bi_s; bj_s = bi_s; pend_A = true; }
            }
            STAGE_B(bj_s, w2 & 3, w2 & 1);     // into just-freed slot
        }
        // Counted wait: retires B_{w+1} (and any A restage issued above),
        // leaves B_{w+2} in flight. Never drains mid-block.
        if (more) { VMWAIT(2); } else { VMWAIT(0); }
        if (kc == 3) {                         // after wait: epilogue stores
            EPILOGUE();                        // don't sit in the vm ledger
            if (++bj_c > 63) { ++bi_c; bj_c = bi_c; }
        }
        __builtin_amdgcn_s_barrier();          // B_{w+1} visible to all waves
    }
}

// ---------------------------------------------------------------------------
// Kernel 3: single block, 1024 threads; writes out[0] directly.
__global__ __launch_bounds__(1024)
void nt_finalize(const float* __restrict__ rowsum,
                 const float* __restrict__ pos,
                 float* __restrict__ out) {
    float v = 0.f;
    for (int i = threadIdx.x; i < NROW; i += 1024) {
        const float pl = pos[i] * INV_T;
        v += logf(__expf(pl) + rowsum[i]) - pl;
    }
    #pragma unroll
    for (int off = 32; off; off >>= 1) v += __shfl_xor(v, off);
    __shared__ float redf[16];
    if ((threadIdx.x & 63) == 0) redf[threadIdx.x >> 6] = v;
    __syncthreads();
    if (threadIdx.x == 0) {
        float s = 0.f;
        #pragma unroll
        for (int w = 0; w < 16; ++w) s += redf[w];
        out[0] = s * (1.0f / NROW);
    }
}

// ---------------------------------------------------------------------------
extern "C" void kernel_launch(void* const* d_in, const int* in_sizes, int n_in,
                              void* d_out, int out_size, void* d_ws, size_t ws_size,
                              hipStream_t stream) {
    const float* z1 = (const float*)d_in[0];
    const float* z2 = (const float*)d_in[1];
    float* out = (float*)d_out;

    char*  zn2    = (char*)d_ws;                                      // 4 MB
    float* rowsum = (float*)((char*)d_ws + (size_t)NROW * DIM * 2);   // 32 KB
    float* pos    = rowsum + NROW;                                    // 32 KB

    nt_normalize<<<NROW / 4, 256, 0, stream>>>(z1, z2, zn2, rowsum);
    nt_gram<<<256, 512, 0, stream>>>(zn2, rowsum, pos);
    nt_finalize<<<1, 1024, 0, stream>>>(rowsum, pos, out);
}